// Round 3
// baseline (324.533 us; speedup 1.0000x reference)
//
#include <hip/hip_runtime.h>

#define P 256
#define C 28
#define NPIX (P * P)            // 65536
#define NB 32                   // batch
#define Q 7                     // float4s per pixel (28 floats)
#define BLK 448                 // 64 pixels * 7 float4s = 7 waves
#define PIX_PER_BLK 64
#define F4_PER_IMG (NPIX * Q)   // 458752

// One fused kernel:
//  - grid = NPIX/64 = 1024 blocks; block owns 64 pixels (all channels),
//    loops over the 32 images.
//  - shifted mask m[i,j,ch] = bk[(i-ch)&255, j, ch] gathered ONCE per thread
//    into a register float4 (4 scalar loads, L2/L3-hot, read-once total 7 MB).
//  - x read as fully coalesced float4 (thread t -> f4 index t within block's
//    7168 B slice), register-prefetched across the reduce syncs.
//  - partial dot4 staged in LDS; 64 threads reduce stride-7 (gcd(7,32)=1 ->
//    2 lanes/bank = free) and store coalesced.
__global__ __launch_bounds__(BLK) void codednet_fused_kernel(
    const float4* __restrict__ x4, const float* __restrict__ bk,
    float* __restrict__ out) {
    __shared__ float s[BLK];
    const int t = threadIdx.x;
    const int p = t / Q;                    // local pixel 0..63
    const int k = t - p * Q;                // f4 slot 0..6
    const int pixbase = blockIdx.x * PIX_PER_BLK;
    const int pixel = pixbase + p;
    const int i = pixel >> 8;
    const int j = pixel & (P - 1);
    const int ch0 = 4 * k;

    // Issue the first x load immediately (independent of the mask gather).
    const float4* xp = x4 + (size_t)blockIdx.x * BLK + t;
    float4 a = xp[0];

    float4 m;
    m.x = bk[(((i - (ch0 + 0)) & (P - 1)) * P + j) * C + (ch0 + 0)];
    m.y = bk[(((i - (ch0 + 1)) & (P - 1)) * P + j) * C + (ch0 + 1)];
    m.z = bk[(((i - (ch0 + 2)) & (P - 1)) * P + j) * C + (ch0 + 2)];
    m.w = bk[(((i - (ch0 + 3)) & (P - 1)) * P + j) * C + (ch0 + 3)];

    for (int b = 0; b < NB; ++b) {
        float4 nxt = a;
        if (b + 1 < NB) nxt = xp[(size_t)(b + 1) * F4_PER_IMG];  // prefetch
        s[t] = a.x * m.x + a.y * m.y + a.z * m.z + a.w * m.w;
        __syncthreads();
        if (t < PIX_PER_BLK) {
            const float* q = s + t * Q;
            out[(size_t)b * NPIX + pixbase + t] =
                ((q[0] + q[1]) + (q[2] + q[3])) + ((q[4] + q[5]) + q[6]);
        }
        __syncthreads();
        a = nxt;
    }
}

extern "C" void kernel_launch(void* const* d_in, const int* in_sizes, int n_in,
                              void* d_out, int out_size, void* d_ws, size_t ws_size,
                              hipStream_t stream) {
    const float* x  = (const float*)d_in[0];
    const float* bk = (const float*)d_in[1];
    float* out = (float*)d_out;
    (void)d_ws; (void)ws_size; (void)in_sizes; (void)n_in; (void)out_size;

    codednet_fused_kernel<<<NPIX / PIX_PER_BLK, BLK, 0, stream>>>(
        (const float4*)x, bk, out);
}